// Round 4
// baseline (458.212 us; speedup 1.0000x reference)
//
#include <hip/hip_runtime.h>
#include <math.h>

typedef int v4i  __attribute__((ext_vector_type(4)));
typedef int v16i __attribute__((ext_vector_type(16)));
typedef short v8s __attribute__((ext_vector_type(8)));
typedef float v16f __attribute__((ext_vector_type(16)));

#define N_IMG 32
#define CIN   256
#define CMID  128
#define COUT  512
#define HWP   3136
#define W58   58
#define PLANE_Q 3456            // 27 tiles of 128
#define CBSTRIDE (PLANE_Q*16)   // 55296 bytes per 16-channel plane
#define IMGSTRIDE (8*CBSTRIDE)  // 442368 bytes per image (128 ch)
#define BSROW 248               // staged halo rows (246 used)
#define GUARD 16384
#define BN_EPS_F 1e-3f
#define ALPHA_F  10.0f
#define ARELU_S  25.5f

// ---------------- workspace layout (float units unless noted) ----------------
#define OFF_WQ1   0            // 32768 fp32 (conv1 folded weights fp32)
#define OFF_WF2   32768        // 147456 fp32 (folded w2, temp)
#define OFF_WF3   180224       // 65536 fp32 (folded w3, temp)
#define OFF_BQ1   245760
#define OFF_BQ2   245888
#define OFF_BQ3   246016
#define OFF_MAX   246528       // 3 uints
#define OFF_Q2    246536       // 128 ints
#define OFF_Q3    246664       // 512 ints
#define OFF_WQ2I  247296       // i8 [9][8 kb][128 m][16] = 147456 B
#define OFF_WQ3I  284160       // i8 [8 kb][512 m][16]    = 65536 B
#define OFF_WBF1  300544       // bf16 [32 kb][128 m][8] = 64 KB
// byte offsets for i8 activation planes:
#define ACT1Q_GUARD_B 52582400u
#define ACT1Q_B       (ACT1Q_GUARD_B + GUARD)

__device__ __forceinline__ void async16(const char* g, char* l) {
    __builtin_amdgcn_global_load_lds((const __attribute__((address_space(1))) void*)g,
                                     (__attribute__((address_space(3))) void*)l, 16, 0, 0);
}

// ---------------- fused: fold BN into weights + |max| (blocks 0..959), fold+quant bias (960..962) ----
__global__ __launch_bounds__(256) void fold_all_kernel(
    const float* __restrict__ w1, const float* __restrict__ g1, const float* __restrict__ v1,
    const float* __restrict__ w2, const float* __restrict__ g2, const float* __restrict__ v2,
    const float* __restrict__ w3, const float* __restrict__ g3, const float* __restrict__ v3,
    const float* __restrict__ b1, const float* __restrict__ be1, const float* __restrict__ m1,
    const float* __restrict__ b2, const float* __restrict__ be2, const float* __restrict__ m2,
    const float* __restrict__ b3, const float* __restrict__ be3, const float* __restrict__ m3,
    float* __restrict__ wq1, float* __restrict__ wf2, float* __restrict__ wf3,
    float* __restrict__ bq1, float* __restrict__ bq2, float* __restrict__ bq3,
    unsigned int* __restrict__ maxw)
{
    __shared__ float red[256];
    const int b = blockIdx.x, t = threadIdx.x;
    if (b < 960) {
        const float *w, *g, *v; float* wf; int inner; unsigned int* mslot; int i;
        if (b < 128)      { w = w1; g = g1; v = v1; wf = wq1; inner = CIN;      mslot = maxw + 0; i = b * 256 + t; }
        else if (b < 704) { w = w2; g = g2; v = v2; wf = wf2; inner = CMID * 9; mslot = maxw + 1; i = (b - 128) * 256 + t; }
        else              { w = w3; g = g3; v = v3; wf = wf3; inner = CMID;     mslot = maxw + 2; i = (b - 704) * 256 + t; }
        int o = i / inner;
        float sc = g[o] / sqrtf(v[o] + BN_EPS_F);
        float val = w[i] * sc;
        wf[i] = val;
        red[t] = fabsf(val);
        __syncthreads();
        for (int s = 128; s > 0; s >>= 1) {
            if (t < s) red[t] = fmaxf(red[t], red[t + s]);
            __syncthreads();
        }
        if (t == 0) atomicMax(mslot, __float_as_uint(red[0]));
    } else {
        const float *bb, *gg, *bebe, *mm, *vv; float* bq; int nn;
        if (b == 960)      { bb = b1; gg = g1; bebe = be1; mm = m1; vv = v1; bq = bq1; nn = CMID; }
        else if (b == 961) { bb = b2; gg = g2; bebe = be2; mm = m2; vv = v2; bq = bq2; nn = CMID; }
        else               { bb = b3; gg = g3; bebe = be3; mm = m3; vv = v3; bq = bq3; nn = COUT; }
        float val0 = 0.f, val1 = 0.f;
        if (t < nn) {
            float sc = gg[t] / sqrtf(vv[t] + BN_EPS_F);
            val0 = (bb[t] - mm[t]) * sc + bebe[t];
        }
        int t2 = t + 256;
        if (t2 < nn) {
            float sc = gg[t2] / sqrtf(vv[t2] + BN_EPS_F);
            val1 = (bb[t2] - mm[t2]) * sc + bebe[t2];
        }
        red[t] = fmaxf(fabsf(val0), fabsf(val1));
        __syncthreads();
        for (int s = 128; s > 0; s >>= 1) {
            if (t < s) red[t] = fmaxf(red[t], red[t + s]);
            __syncthreads();
        }
        float mx = fmaxf(red[0], 1e-8f);
        float s = 32767.0f / mx;
        if (t < nn)  bq[t]  = rintf(val0 * s) / s;
        if (t2 < nn) bq[t2] = rintf(val1 * s) / s;
    }
}

// ---------------- fused quantization: w1->bf16 (0..127), w2->i8 (128..255), w3->i8 (256..511) ----
__global__ __launch_bounds__(256) void quant_all_kernel(
    const float* __restrict__ wq1f, const float* __restrict__ wf2, const float* __restrict__ wf3,
    const unsigned int* __restrict__ maxw,
    unsigned short* __restrict__ wbf, char* __restrict__ wq2i, char* __restrict__ wq3i,
    int* __restrict__ Q2, int* __restrict__ Q3)
{
    __shared__ int red[256];
    const int b = blockIdx.x, t = threadIdx.x;
    if (b < 128) {
        int i = b * 256 + t;
        float s = 127.0f / fmaxf(__uint_as_float(maxw[0]), 1e-8f);
        int kb = i >> 10, rem = i & 1023;
        int m = rem >> 3, j = rem & 7;
        int c = kb * 8 + j;
        float k = rintf(wq1f[m * CIN + c] * s);
        wbf[i] = (unsigned short)(__float_as_uint(k) >> 16);
    } else if (b < 256) {
        int m = b - 128;
        float s = 127.0f / fmaxf(__uint_as_float(maxw[1]), 1e-8f);
        int sum = 0;
        for (int idx = t; idx < CMID * 9; idx += 256) {
            int c = idx / 9, tap = idx - c * 9;
            int q = (int)rintf(wf2[(size_t)m * (CMID * 9) + idx] * s);
            wq2i[(size_t)tap * 16384 + (c >> 4) * 2048 + m * 16 + (c & 15)] = (char)q;
            sum += q;
        }
        red[t] = sum;
        __syncthreads();
        for (int st = 128; st > 0; st >>= 1) {
            if (t < st) red[t] += red[t + st];
            __syncthreads();
        }
        if (t == 0) Q2[m] = red[0];
    } else {
        int m = (b - 256) * 2 + (t >> 7), c = t & 127;
        float s = 127.0f / fmaxf(__uint_as_float(maxw[2]), 1e-8f);
        int q = (int)rintf(wf3[(size_t)m * CMID + c] * s);
        wq3i[(size_t)(c >> 4) * 8192 + m * 16 + (c & 15)] = (char)q;
        red[t] = q;
        __syncthreads();
        for (int st = 64; st > 0; st >>= 1) {
            if ((t & 127) < st) red[t] += red[t + st];
            __syncthreads();
        }
        if ((t & 127) == 0) Q3[m] = red[t];
    }
}

// ---------------- conv1: 1x1 bf16 MFMA (exact trunc 3-split) + qrelu -> packed i8 ----------------
// Pipelined: chunk kc+1's x loads issue right after chunk kc's split consumes the regs,
// so HBM latency hides under the MFMA phase. Epilogue packs dwords directly into the
// [cb][q][16] layout in LDS, then stores 1KB-contiguous per wave.
#define LOADX(KC) do {                                                        \
    const float* chbase = Xn + (size_t)((KC) * 64 + skb * 8) * HWP;           \
    _Pragma("unroll")                                                         \
    for (int j = 0; j < 8; j++) {                                             \
        const float* cp = chbase + (size_t)j * HWP;                           \
        if (fast) {                                                           \
            float4 f = *(const float4*)(cp + p_[0]);                          \
            v[j][0] = f.x; v[j][1] = f.y; v[j][2] = f.z; v[j][3] = f.w;       \
        } else {                                                              \
            _Pragma("unroll")                                                 \
            for (int e = 0; e < 4; e++) v[j][e] = cp[p_[e]];                  \
        }                                                                     \
    }                                                                         \
} while (0)

__global__ __launch_bounds__(256, 3) void conv1_bf16_kernel(
    const float* __restrict__ X, const unsigned short* __restrict__ Wbf,
    const unsigned int* __restrict__ maxw, const float* __restrict__ bq1,
    char* __restrict__ act1q)
{
    __shared__ char lds[49152];
    char* Bh = lds;             // [8 kb][128 q][16]  x hi
    char* Bm = lds + 16384;     //                    x mid
    char* Bl = lds + 32768;     //                    x lo
    const int tid = threadIdx.x;
    const int n  = blockIdx.z;
    const int q0 = blockIdx.x * 128;
    const int lane = tid & 63, wid = tid >> 6;
    const int lo = lane & 31, hi = lane >> 5;
    const int wm = wid >> 1, wn = wid & 1;
    const float* Xn = X + (size_t)n * CIN * HWP;

    const int skb = tid >> 5, sqq = tid & 31;
    const int qq0 = q0 + sqq * 4;
    int p_[4];
#pragma unroll
    for (int e = 0; e < 4; e++) {
        int q = qq0 + e;
        int y = q / W58, xx = q - y * W58;
        int p = (y - 1) * 56 + (xx - 1);
        p_[e] = p < 0 ? 0 : (p > HWP - 1 ? HWP - 1 : p);
    }
    const bool fast = (p_[1] == p_[0] + 1) && (p_[2] == p_[0] + 2) && (p_[3] == p_[0] + 3);

    v16f acc[2][2] = {};
    float v[8][4];
    LOADX(0);                                 // preload chunk 0

    for (int kc = 0; kc < 4; kc++) {          // 4 chunks of 64 input channels
        __syncthreads();                      // prior chunk's LDS reads done
        // split current chunk (consumes v) -> LDS
#pragma unroll
        for (int e = 0; e < 4; e++) {
            unsigned ph[4], pm_[4], pl[4];
#pragma unroll
            for (int jj = 0; jj < 4; jj++) {
                float a0 = v[2 * jj][e], a1 = v[2 * jj + 1][e];
                unsigned u0 = __float_as_uint(a0), u1 = __float_as_uint(a1);
                unsigned h0 = u0 & 0xFFFF0000u, h1 = u1 & 0xFFFF0000u;
                float r0 = a0 - __uint_as_float(h0), r1 = a1 - __uint_as_float(h1);
                unsigned w0 = __float_as_uint(r0) & 0xFFFF0000u;
                unsigned w1 = __float_as_uint(r1) & 0xFFFF0000u;
                float s0 = r0 - __uint_as_float(w0), s1 = r1 - __uint_as_float(w1);
                unsigned l0 = __float_as_uint(s0) & 0xFFFF0000u;
                unsigned l1 = __float_as_uint(s1) & 0xFFFF0000u;
                ph[jj]  = (h0 >> 16) | h1;
                pm_[jj] = (w0 >> 16) | w1;
                pl[jj]  = (l0 >> 16) | l1;
            }
            int off = (skb * 128 + sqq * 4 + e) * 16;
            *(uint4*)(Bh + off) = make_uint4(ph[0], ph[1], ph[2], ph[3]);
            *(uint4*)(Bm + off) = make_uint4(pm_[0], pm_[1], pm_[2], pm_[3]);
            *(uint4*)(Bl + off) = make_uint4(pl[0], pl[1], pl[2], pl[3]);
        }
        if (kc < 3) LOADX(kc + 1);            // issue next chunk now; lands during MFMA
        __syncthreads();                      // staging visible

        const char* wbase = (const char*)Wbf + kc * 16384;
#pragma unroll
        for (int ks = 0; ks < 4; ks++) {
            v8s a[2];
#pragma unroll
            for (int s = 0; s < 2; s++)
                a[s] = *(const v8s*)(wbase + (((ks * 2 + hi) * 128) + wm * 64 + s * 32 + lo) * 16);
#pragma unroll
            for (int pass = 0; pass < 3; pass++) {
                const char* Bp = (pass == 0) ? Bh : ((pass == 1) ? Bm : Bl);
                v8s b[2];
#pragma unroll
                for (int t = 0; t < 2; t++)
                    b[t] = *(const v8s*)(Bp + ((ks * 2 + hi) * 128 + wn * 64 + t * 32 + lo) * 16);
#pragma unroll
                for (int s = 0; s < 2; s++)
#pragma unroll
                    for (int t = 0; t < 2; t++)
                        acc[s][t] = __builtin_amdgcn_mfma_f32_32x32x16_bf16(a[s], b[t], acc[s][t], 0, 0, 0);
            }
        }
    }

    // epilogue: dequant + bias + qrelu -> dwords directly in [cb][q][16] layout
    float inv_s = fmaxf(__uint_as_float(maxw[0]), 1e-8f) / 127.0f;
    __syncthreads();                          // all LDS reads done before overwrite
    char* Ls = lds;                           // [8 cb][128 q][16]
#pragma unroll
    for (int s = 0; s < 2; s++)
#pragma unroll
        for (int t = 0; t < 2; t++) {
            int qloc = wn * 64 + t * 32 + lo;
            int cb0 = wm * 4 + 2 * s;
#pragma unroll
            for (int g = 0; g < 4; g++) {
                unsigned d = 0;
#pragma unroll
                for (int r = 0; r < 4; r++) {
                    int m = wm * 64 + s * 32 + r + 8 * g + 4 * hi;
                    float val = fmaf(acc[s][t][g * 4 + r], inv_s, bq1[m]);
                    val = fminf(fmaxf(val, 0.f), ALPHA_F);
                    int k1 = (int)rintf(val * ARELU_S);
                    d |= (unsigned)((k1 - 128) & 255) << (8 * r);
                }
                *(unsigned*)(Ls + (cb0 + (g >> 1)) * 2048 + qloc * 16 + (g & 1) * 8 + 4 * hi) = d;
            }
        }
    __syncthreads();
    char* dst = act1q + (size_t)n * IMGSTRIDE + (size_t)q0 * 16;
#pragma unroll
    for (int it = 0; it < 4; it++) {
        int idx = it * 256 + tid;             // 0..1023 -> (cb, q); wave writes 1KB contiguous
        int cb = idx >> 7, ql = idx & 127;
        int q = q0 + ql;
        int y = q / W58, xx = q - y * W58;
        int4 w;
        if ((unsigned)(y - 1) < 56u && (unsigned)(xx - 1) < 56u)
            w = *(const int4*)(Ls + cb * 2048 + ql * 16);
        else
            w = make_int4(0x80808080, 0x80808080, 0x80808080, 0x80808080);
        *(int4*)(dst + (size_t)cb * CBSTRIDE + ql * 16) = w;
    }
}

// ---------------- fused conv2 (3x3 i8 MFMA + qrelu) -> LDS -> conv3 (1x1 i8 MFMA) -> fp32 out ----
// conv2 epilogue packs dwords DIRECTLY into Ps (no Bs overlay, so no pre-barrier needed);
// only 2 barriers total.
__global__ __launch_bounds__(256, 3) void conv23_i8_kernel(
    const char* __restrict__ actq, const char* __restrict__ wq2i,
    const char* __restrict__ wq3i,
    const int* __restrict__ Q2, const float* __restrict__ bq2,
    const int* __restrict__ Q3, const float* __restrict__ bq3,
    const unsigned int* __restrict__ maxw, float* __restrict__ out)
{
    __shared__ char lds[48128];
    char* Bs = lds;              // [8 cb][BSROW q][16] act1 halo
    char* Ps = lds + 31744;      // [8 cb][128 q][16] conv2 i8 result
    const int tid = threadIdx.x;
    const int n  = blockIdx.z;
    const int q0 = blockIdx.x * 128;
    const int lane = tid & 63, wid = tid >> 6;
    const int lo = lane & 31, hi = lane >> 5;
    const int wm = wid >> 1, wn = wid & 1;

    // ---- conv2 phase ----
    const char* src = actq + (size_t)n * IMGSTRIDE + (long)(q0 - 59) * 16;
#pragma unroll
    for (int cb = 0; cb < 8; cb++) {
        if (tid < 246)
            async16(src + (size_t)cb * CBSTRIDE + tid * 16, Bs + cb * (BSROW * 16) + tid * 16);
    }
    __syncthreads();                          // B staged (barrier drains LDS-DMA)

    v16i acc[2][2] = {};
    for (int tap = 0; tap < 9; tap++) {
        const char* wt = wq2i + (size_t)tap * 16384;
        const int tapoff = ((tap / 3) - 1) * W58 + (tap % 3) - 1;
#pragma unroll
        for (int ks = 0; ks < 4; ks++) {
            v4i a[2], b[2];
#pragma unroll
            for (int s = 0; s < 2; s++)
                a[s] = *(const v4i*)(wt + (ks * 2 + hi) * 2048 + (wm * 64 + s * 32 + lo) * 16);
#pragma unroll
            for (int t = 0; t < 2; t++) {
                int ql = 59 + tapoff + wn * 64 + t * 32 + lo;
                b[t] = *(const v4i*)(Bs + ((ks * 2 + hi) * BSROW + ql) * 16);
            }
#pragma unroll
            for (int s = 0; s < 2; s++)
#pragma unroll
                for (int t = 0; t < 2; t++)
                    acc[s][t] = __builtin_amdgcn_mfma_i32_32x32x32_i8(a[s], b[t], acc[s][t], 0, 0, 0);
        }
    }

    // qrelu -> dwords directly into Ps [cb][q][16] (Ps doesn't alias Bs: no barrier needed)
    float scale2 = fmaxf(__uint_as_float(maxw[1]), 1e-8f) / (127.0f * ARELU_S);
#pragma unroll
    for (int s = 0; s < 2; s++)
#pragma unroll
        for (int t = 0; t < 2; t++) {
            int qloc = wn * 64 + t * 32 + lo;
            int cb0 = wm * 4 + 2 * s;
#pragma unroll
            for (int g = 0; g < 4; g++) {
                unsigned d = 0;
#pragma unroll
                for (int r = 0; r < 4; r++) {
                    int m = wm * 64 + s * 32 + r + 8 * g + 4 * hi;
                    float val = fmaf((float)(acc[s][t][g * 4 + r] + 128 * Q2[m]), scale2, bq2[m]);
                    val = fminf(fmaxf(val, 0.f), ALPHA_F);
                    int k2 = (int)rintf(val * ARELU_S);
                    d |= (unsigned)((k2 - 128) & 255) << (8 * r);
                }
                *(unsigned*)(Ps + (cb0 + (g >> 1)) * 2048 + qloc * 16 + (g & 1) * 8 + 4 * hi) = d;
            }
        }
    __syncthreads();                          // Ps visible to all waves

    // ---- conv3 phase ----
    float scale3 = fmaxf(__uint_as_float(maxw[2]), 1e-8f) / (127.0f * ARELU_S);
    // hoist B fragments (reused by all 4 m-blocks)
    v4i bf[4][2];
#pragma unroll
    for (int ks = 0; ks < 4; ks++)
#pragma unroll
        for (int t = 0; t < 2; t++)
            bf[ks][t] = *(const v4i*)(Ps + (ks * 2 + hi) * 2048 + (wn * 64 + t * 32 + lo) * 16);

    const int qq = q0 + wn * 64 + lo;
#pragma unroll
    for (int m0i = 0; m0i < 4; m0i++) {
        const int m0 = m0i * 128;
        v16i acc3[2][2] = {};
#pragma unroll
        for (int ks = 0; ks < 4; ks++) {
            v4i a[2];
#pragma unroll
            for (int s = 0; s < 2; s++)
                a[s] = *(const v4i*)(wq3i + (ks * 2 + hi) * 8192 + (m0 + wm * 64 + s * 32 + lo) * 16);
#pragma unroll
            for (int s = 0; s < 2; s++)
#pragma unroll
                for (int t = 0; t < 2; t++)
                    acc3[s][t] = __builtin_amdgcn_mfma_i32_32x32x32_i8(a[s], bf[ks][t], acc3[s][t], 0, 0, 0);
        }
#pragma unroll
        for (int s = 0; s < 2; s++)
#pragma unroll
            for (int t = 0; t < 2; t++) {
                int q = qq + t * 32;
                int y = q / W58, x = q - y * W58;
                if ((unsigned)(y - 1) < 56u && (unsigned)(x - 1) < 56u) {
                    int p = (y - 1) * 56 + (x - 1);
                    float* op = out + (size_t)n * COUT * HWP + p;
#pragma unroll
                    for (int reg = 0; reg < 16; reg++) {
                        int m = m0 + wm * 64 + s * 32 + (reg & 3) + 8 * (reg >> 2) + 4 * hi;
                        op[(size_t)m * HWP] = fmaf((float)(acc3[s][t][reg] + 128 * Q3[m]), scale3, bq3[m]);
                    }
                }
            }
    }
}

extern "C" void kernel_launch(void* const* d_in, const int* in_sizes, int n_in,
                              void* d_out, int out_size, void* d_ws, size_t ws_size,
                              hipStream_t stream) {
    const float* x   = (const float*)d_in[0];
    const float* w1  = (const float*)d_in[1];
    const float* b1  = (const float*)d_in[2];
    const float* g1  = (const float*)d_in[3];
    const float* be1 = (const float*)d_in[4];
    const float* m1  = (const float*)d_in[5];
    const float* v1  = (const float*)d_in[6];
    const float* w2  = (const float*)d_in[7];
    const float* b2  = (const float*)d_in[8];
    const float* g2  = (const float*)d_in[9];
    const float* be2 = (const float*)d_in[10];
    const float* m2  = (const float*)d_in[11];
    const float* v2  = (const float*)d_in[12];
    const float* w3  = (const float*)d_in[13];
    const float* b3  = (const float*)d_in[14];
    const float* g3  = (const float*)d_in[15];
    const float* be3 = (const float*)d_in[16];
    const float* m3  = (const float*)d_in[17];
    const float* v3  = (const float*)d_in[18];

    float* ws  = (float*)d_ws;
    unsigned char* wsb = (unsigned char*)d_ws;
    float* wq1 = ws + OFF_WQ1;
    float* wf2 = ws + OFF_WF2;
    float* wf3 = ws + OFF_WF3;
    float* bq1 = ws + OFF_BQ1;
    float* bq2 = ws + OFF_BQ2;
    float* bq3 = ws + OFF_BQ3;
    unsigned int* maxw = (unsigned int*)(ws + OFF_MAX);
    int* Q2 = (int*)(ws + OFF_Q2);
    int* Q3 = (int*)(ws + OFF_Q3);
    char* wq2i = (char*)(ws + OFF_WQ2I);
    char* wq3i = (char*)(ws + OFF_WQ3I);
    unsigned short* wbf = (unsigned short*)(ws + OFF_WBF1);
    char* act1q = (char*)(wsb + ACT1Q_B);
    float* out  = (float*)d_out;

    hipMemsetAsync(maxw, 0, 12, stream);

    fold_all_kernel<<<963, 256, 0, stream>>>(
        w1, g1, v1, w2, g2, v2, w3, g3, v3,
        b1, be1, m1, b2, be2, m2, b3, be3, m3,
        wq1, wf2, wf3, bq1, bq2, bq3, maxw);

    quant_all_kernel<<<512, 256, 0, stream>>>(wq1, wf2, wf3, maxw, wbf, wq2i, wq3i, Q2, Q3);

    // conv1 (bf16 MFMA, exact split, pipelined) -> act1q, pad rows written in-kernel
    conv1_bf16_kernel<<<dim3(27, 1, 32), 256, 0, stream>>>(x, wbf, maxw, bq1, act1q);
    // fused conv2+conv3: act2 lives only in LDS
    conv23_i8_kernel<<<dim3(27, 1, 32), 256, 0, stream>>>(act1q, wq2i, wq3i, Q2, bq2, Q3, bq3, maxw, out);
}